// Round 1
// baseline (112.159 us; speedup 1.0000x reference)
//
#include <hip/hip_runtime.h>

// QuantumMeasurement: exp[b,q] = sum_i (re^2+im^2)[b,i] * (-1)^{bit_{9-q}(i)}
// Pauli-Z is diagonal: never read the 80 MB observable. Pure streaming
// reduction, 64 MB in, 320 KB out. One 64-lane wave per batch row.
//
// v2 changes vs 112 µs baseline:
//  - all 8 global_load_dwordx4 issued up front (8 in flight per wave)
//  - signed Walsh-Hadamard butterfly: 6 shuffles extract ALL 6 lane-bit
//    qubits (lane 1<<k holds qubit 7-k) instead of 6+15+... = 21
//  - 4 plain-sum accumulators reduced via LDS transpose (1 ds_write_b128 +
//    4 ds_read_b32 + 4 shfl in 16-lane groups) instead of 4x6 shuffles
//  - epilogue DS ops 45 -> 13; output stored from 10 distinct lanes in one
//    predicated wave store instead of 10 serial lane-0 stores

#define BATCH 8192
#define DIM   1024
#define NQ    10

__global__ __launch_bounds__(256, 8) void qmeas_kernel(
    const float* __restrict__ sre,
    const float* __restrict__ sim,
    float* __restrict__ out)
{
    const int row  = (int)((blockIdx.x * blockDim.x + threadIdx.x) >> 6);
    const int lane = (int)(threadIdx.x & 63);
    const int wv   = (int)(threadIdx.x >> 6);   // wave id within block (0..3)

    const float4* __restrict__ rowR = (const float4*)(sre + (size_t)row * DIM);
    const float4* __restrict__ rowI = (const float4*)(sim + (size_t)row * DIM);

    // element index i = 4*(lane + 64*it) + c
    //   bits 0,1 of i = c     -> qubits 9,8  (intra-float4 signed combos)
    //   bits 2..7 of i = lane -> qubits 7..2 (signed WHT butterfly)
    //   bits 8,9 of i = it    -> qubits 1,0  (compile-time signs)

    // issue all 8 loads back-to-back: 8 outstanding vmem ops per wave
    float4 r0 = rowR[lane];       float4 r1 = rowR[lane + 64];
    float4 r2 = rowR[lane + 128]; float4 r3 = rowR[lane + 192];
    float4 m0 = rowI[lane];       float4 m1 = rowI[lane + 64];
    float4 m2 = rowI[lane + 128]; float4 m3 = rowI[lane + 192];

    float tot = 0.f, a8 = 0.f, a9 = 0.f, aq0 = 0.f, aq1 = 0.f;

#define ACC(rr, mm, it) do {                                    \
        float p0 = fmaf(rr.x, rr.x, mm.x * mm.x);               \
        float p1 = fmaf(rr.y, rr.y, mm.y * mm.y);               \
        float p2 = fmaf(rr.z, rr.z, mm.z * mm.z);               \
        float p3 = fmaf(rr.w, rr.w, mm.w * mm.w);               \
        float pa = p0 + p1, pb = p2 + p3;                       \
        float pe = p0 - p1, pf = p2 - p3;                       \
        float ps = pa + pb;                                     \
        a9  += pe + pf;              /* qubit 9: bit0 of i */   \
        a8  += pa - pb;              /* qubit 8: bit1 of i */   \
        tot += ps;                                              \
        aq1 += ((it) & 1) ? -ps : ps; /* qubit 1: bit8 of i */  \
        aq0 += ((it) & 2) ? -ps : ps; /* qubit 0: bit9 of i */  \
    } while (0)

    ACC(r0, m0, 0);
    ACC(r1, m1, 1);
    ACC(r2, m2, 2);
    ACC(r3, m3, 3);
#undef ACC

    // ---- signed Walsh-Hadamard butterfly on tot (6 shuffles total) ----
    // After level k: s(L) = sum_j (-1)^{popcount(L&j)} tot(j) over processed
    // bits. Final: lane L = 1<<k holds sum_j (-1)^{bit_k(j)} tot_j, i.e.
    // qubit 7-k (lane bit k is bit k+2 of i).
    float s = tot;
#pragma unroll
    for (int k = 0; k < 6; ++k) {
        float y = __shfl_xor(s, 1 << k);
        s = (lane & (1 << k)) ? (y - s) : (s + y);
    }

    // ---- LDS transpose for the 4 plain sums (aq0, aq1, a8, a9) ----
    // write: lane -> [aq0 aq1 a8 a9] (ds_write_b128, conflict-free: lanes
    // 0..7 cover all 32 banks once). read: 16-lane group g sums accumulator
    // g; 2-way bank aliasing only (free).
    __shared__ float xp[4][64][4];
    xp[wv][lane][0] = aq0;
    xp[wv][lane][1] = aq1;
    xp[wv][lane][2] = a8;
    xp[wv][lane][3] = a9;
    __syncthreads();

    const int g = lane >> 4;      // which accumulator this group reduces
    const int m = lane & 15;
    float v0 = xp[wv][m     ][g];
    float v1 = xp[wv][m + 16][g];
    float v2 = xp[wv][m + 32][g];
    float v3 = xp[wv][m + 48][g];
    float sum4 = (v0 + v1) + (v2 + v3);
#pragma unroll
    for (int d = 1; d < 16; d <<= 1)   // stays within the 16-lane group
        sum4 += __shfl_xor(sum4, d);

    // ---- one predicated wave store: 10 lanes write 10 contiguous floats --
    // WHT lanes 1,2,4,8,16,32 -> qubits 7,6,5,4,3,2
    // group reps 3,19,35,51   -> qubits 0,1,8,9 (avoid WHT lanes)
    int   q   = -1;
    float val = 0.f;
    if      (lane == 1)  { q = 7; val = s; }
    else if (lane == 2)  { q = 6; val = s; }
    else if (lane == 4)  { q = 5; val = s; }
    else if (lane == 8)  { q = 4; val = s; }
    else if (lane == 16) { q = 3; val = s; }
    else if (lane == 32) { q = 2; val = s; }
    else if (lane == 3)  { q = 0; val = sum4; }
    else if (lane == 19) { q = 1; val = sum4; }
    else if (lane == 35) { q = 8; val = sum4; }
    else if (lane == 51) { q = 9; val = sum4; }
    if (q >= 0)
        out[(size_t)row * NQ + q] = val;
}

extern "C" void kernel_launch(void* const* d_in, const int* in_sizes, int n_in,
                              void* d_out, int out_size, void* d_ws, size_t ws_size,
                              hipStream_t stream) {
    const float* sre = (const float*)d_in[0];
    const float* sim = (const float*)d_in[1];
    // d_in[2] (pauli_z_obs) intentionally unused: diagonal signs are analytic.
    float* out = (float*)d_out;

    dim3 grid(BATCH / 4), block(256);   // 4 waves (rows) per block, 8192 waves
    qmeas_kernel<<<grid, block, 0, stream>>>(sre, sim, out);
}